// Round 1
// baseline (136.181 us; speedup 1.0000x reference)
//
#include <hip/hip_runtime.h>

// MomentConv2d: B=32, CIN=16, COUT=32, H=W=14, K=5, S=2 -> OH=OW=5
// out = (mean [32,32,5,5], cov [32,32,5,5,5,5]) concatenated, f32.
//
// cov[b,i,p,q,r,s] = sum_c sum_{a,bb,cc,d} w[i,a,bb] w[i,cc,d]
//                    * C[b,c, p*2+a, q*2+bb, r*2+cc, s*2+d]
// Strategy: reduce over c first (16x work cut), then two separable 5x5 convs.

#define NB   32
#define NCIN 16
#define NCO  32
#define HH   14
#define OO   5
#define HW   196          // 14*14
#define T1_PER_BI 4900    // 196*25

// Intermediate T1[b][i][h1][w1][rs], rs = r*5+s  (20 MB, static device scratch)
__device__ float g_T1[NB * NCO * T1_PER_BI];

// ---------------------------------------------------------------------------
// Kernel 1: one block per (b, h1).
//  Phase 1: CS[w1][h2][w2] = sum_c C[b,c,h1,w1,h2,w2]   (LDS, padded rows)
//  Phase 2: thread (i,w1): T1[rs] = sum_{cc,d} w[i,cc,d] * CS[w1, 2r+cc, 2s+d]
//  Phase 3: LDS transpose + coalesced global write of T1 slab.
// ---------------------------------------------------------------------------
__global__ __launch_bounds__(448) void k1_reduce_conv(const float* __restrict__ C,
                                                      const float* __restrict__ w) {
  const int blk = blockIdx.x;          // 0..447
  const int b   = blk / HH;
  const int h1  = blk % HH;
  const int tid = threadIdx.x;         // 0..447

  __shared__ float wl[NCO * 25];       // 800 floats
  __shared__ float cs[14 * 224];       // [w1][h2][w2 padded to 16] = 3136 floats
  __shared__ float t1s[448 * 25];      // [i][w1][rs] = 11200 floats

  for (int t = tid; t < NCO * 25; t += 448) wl[t] = w[t];

  // ---- phase 1: cin reduction, float4-coalesced ----
  const float4* C4 = (const float4*)C;
  const int base4 = ((b * NCIN) * HH + h1) * 686;   // 2744/4 float4 per (b,c,h1)
  for (int j4 = tid; j4 < 686; j4 += 448) {
    float4 acc = make_float4(0.f, 0.f, 0.f, 0.f);
    #pragma unroll
    for (int c = 0; c < NCIN; ++c) {
      float4 v = C4[base4 + c * 9604 + j4];         // c stride = 38416/4
      acc.x += v.x; acc.y += v.y; acc.z += v.z; acc.w += v.w;
    }
    const float vv[4] = {acc.x, acc.y, acc.z, acc.w};
    const int j = j4 * 4;
    #pragma unroll
    for (int e = 0; e < 4; ++e) {
      const int jj = j + e;
      const int w1 = jj / 196, rem = jj % 196;
      const int h2 = rem / 14, w2 = rem % 14;
      cs[w1 * 224 + h2 * 16 + w2] = vv[e];
    }
  }
  __syncthreads();

  // ---- phase 2: conv over second index pair ----
  const int i  = tid & 31;             // output channel
  const int w1 = tid >> 5;             // 0..13
  float wr[25];
  #pragma unroll
  for (int t = 0; t < 25; ++t) wr[t] = wl[i * 25 + t];

  float acc[25];
  #pragma unroll
  for (int t = 0; t < 25; ++t) acc[t] = 0.f;

  #pragma unroll
  for (int r = 0; r < 5; ++r) {
    #pragma unroll
    for (int cc = 0; cc < 5; ++cc) {
      const int row = 2 * r + cc;
      const float4* rp = (const float4*)(cs + w1 * 224 + row * 16); // 64B aligned
      float4 x0 = rp[0], x1 = rp[1], x2 = rp[2], x3 = rp[3];        // broadcast reads
      const float col[16] = {x0.x, x0.y, x0.z, x0.w,
                             x1.x, x1.y, x1.z, x1.w,
                             x2.x, x2.y, x2.z, x2.w,
                             x3.x, x3.y, x3.z, x3.w};
      #pragma unroll
      for (int s = 0; s < 5; ++s) {
        #pragma unroll
        for (int d = 0; d < 5; ++d)
          acc[r * 5 + s] += wr[cc * 5 + d] * col[2 * s + d];
      }
    }
  }

  // ---- phase 3: stage to LDS, write T1 slab coalesced ----
  #pragma unroll
  for (int t = 0; t < 25; ++t) t1s[i * 350 + w1 * 25 + t] = acc[t];
  __syncthreads();

  // T1 global index for (b,i,h1,w1,rs) = (b*32+i)*4900 + h1*350 + w1*25 + rs
  const size_t gbase = (size_t)b * NCO * T1_PER_BI + (size_t)h1 * 350;
  for (int idx = tid; idx < 11200; idx += 448) {
    const int i2 = idx / 350, rem = idx % 350;     // rem = w1*25 + rs
    g_T1[gbase + (size_t)i2 * T1_PER_BI + rem] = t1s[idx];
  }
}

// ---------------------------------------------------------------------------
// Kernel 2: blocks 0..1023 -> cov for (b,i); blocks 1024..1055 -> mean for b.
// ---------------------------------------------------------------------------
__global__ __launch_bounds__(128) void k2_out(const float* __restrict__ u,
                                              const float* __restrict__ w,
                                              float* __restrict__ out) {
  const int blk = blockIdx.x;
  const int tid = threadIdx.x;

  if (blk < NB * NCO) {
    // ---- covariance path: conv over first index pair ----
    __shared__ float sl[T1_PER_BI];                  // 19.6 KB
    const float4* src = (const float4*)(g_T1 + (size_t)blk * T1_PER_BI);
    float4* sl4 = (float4*)sl;
    for (int j = tid; j < 1225; j += 128) sl4[j] = src[j];

    const int i = blk & 31;
    float wr[25];
    #pragma unroll
    for (int t = 0; t < 25; ++t) wr[t] = w[i * 25 + t];  // uniform -> s_load
    __syncthreads();

    for (int o = tid; o < 625; o += 128) {           // o = ((p*5+q)*5+r)*5+s
      const int p  = o / 125;
      const int q  = (o / 25) % 5;
      const int rs = o % 25;
      float acc = 0.f;
      #pragma unroll
      for (int a = 0; a < 5; ++a) {
        #pragma unroll
        for (int bb = 0; bb < 5; ++bb)
          acc += wr[a * 5 + bb] * sl[((2 * p + a) * 14 + (2 * q + bb)) * 25 + rs];
      }
      out[25600 + blk * 625 + o] = acc;
    }
  } else {
    // ---- mean path ----
    const int b = blk - NB * NCO;
    __shared__ float us[HW];
    for (int j = tid; j < HW; j += 128) {
      float acc = 0.f;
      #pragma unroll
      for (int c = 0; c < NCIN; ++c) acc += u[(b * NCIN + c) * HW + j];
      us[j] = acc;
    }
    __syncthreads();
    for (int o = tid; o < NCO * 25; o += 128) {      // o = i*25 + p*5 + q
      const int i = o / 25;
      const int p = (o / 5) % 5;
      const int q = o % 5;
      float acc = 0.f;
      #pragma unroll
      for (int a = 0; a < 5; ++a) {
        #pragma unroll
        for (int bb = 0; bb < 5; ++bb)
          acc += w[i * 25 + a * 5 + bb] * us[(2 * p + a) * 14 + 2 * q + bb];
      }
      out[b * 800 + o] = acc;
    }
  }
}

extern "C" void kernel_launch(void* const* d_in, const int* in_sizes, int n_in,
                              void* d_out, int out_size, void* d_ws, size_t ws_size,
                              hipStream_t stream) {
  const float* u = (const float*)d_in[0];   // [32,16,14,14]
  const float* C = (const float*)d_in[1];   // [32,16,14,14,14,14]
  const float* w = (const float*)d_in[2];   // [32,1,5,5]
  float* out = (float*)d_out;               // 25600 mean + 640000 cov, f32

  hipLaunchKernelGGL(k1_reduce_conv, dim3(NB * HH), dim3(448), 0, stream, C, w);
  hipLaunchKernelGGL(k2_out, dim3(NB * NCO + NB), dim3(128), 0, stream, u, w, out);
}